// Round 3
// baseline (98.999 us; speedup 1.0000x reference)
//
#include <hip/hip_runtime.h>
#include <hip/hip_bf16.h>

#define B_ 4
#define N_ 2048
#define D_ 1024
#define H_ 8
#define HD_ 128

typedef __attribute__((ext_vector_type(4))) float f32x4;
typedef __attribute__((ext_vector_type(8))) short bf16x8;

__device__ __forceinline__ short f2bf(float f) {
    unsigned u = __builtin_bit_cast(unsigned, f);
    u = (u + 0x7FFFu + ((u >> 16) & 1u)) >> 16;   // round-to-nearest-even
    return (short)u;
}
__device__ __forceinline__ float bf2f(unsigned short s) {
    unsigned u = (unsigned)s << 16;
    return __builtin_bit_cast(float, u);
}

typedef const __attribute__((address_space(1))) void* gas_t;
typedef __attribute__((address_space(3))) void* las_t;

__device__ __forceinline__ void gload16(const void* g, void* l) {
    // lane i's 16B from per-lane g -> wave-uniform LDS base + lane*16
    __builtin_amdgcn_global_load_lds((gas_t)g, (las_t)l, 16, 0, 0);
}

// ---------------------------------------------------------------------------
// Kernel 0: fp32 -> bf16 pack for h (4096 blocks) and Wr (512 blocks), fused.
// ---------------------------------------------------------------------------
__global__ __launch_bounds__(256) void k_cvt(
    const float* __restrict__ h, short* __restrict__ hb,
    const float* __restrict__ Wr, short* __restrict__ wrb)
{
    int blk = blockIdx.x;
    const float* src;
    short* dst;
    int i;
    if (blk < 4096) { src = h;  dst = hb;  i = blk * 256 + threadIdx.x; }
    else            { src = Wr; dst = wrb; i = (blk - 4096) * 256 + threadIdx.x; }
    float4 a = ((const float4*)src)[i * 2];
    float4 b = ((const float4*)src)[i * 2 + 1];
    bf16x8 o;
    o[0] = f2bf(a.x); o[1] = f2bf(a.y); o[2] = f2bf(a.z); o[3] = f2bf(a.w);
    o[4] = f2bf(b.x); o[5] = f2bf(b.y); o[6] = f2bf(b.z); o[7] = f2bf(b.w);
    ((bf16x8*)dst)[i] = o;
}

// ---------------------------------------------------------------------------
// Kernel 1: m97-structure GEMM (128x128 tile, BK=64, global_load_lds x16B)
// computing fr = h @ Wr^T, fused epilogue:
//   sr[b,head,j] = sum_c leaky(fr[j, head*128+c]) * att_r[c]
// Grid: 512 blocks (64 row-tiles x 8 heads), XCD head-chunked swizzle.
// Block 256 thr = 4 waves (2x2 of 64x64 sub-tiles, 4x4 16x16 frags each).
// ---------------------------------------------------------------------------
__global__ __launch_bounds__(256) void k_proj_sr(
    const short* __restrict__ hb, const short* __restrict__ wrb,
    const float* __restrict__ att_r, float* __restrict__ sr)
{
    __shared__ short sA[128 * 64];     // 16 KB, row-major [128][64]
    __shared__ short sB[128 * 64];     // 16 KB
    __shared__ float part[2][128];

    const int tid  = threadIdx.x;
    const int lane = tid & 63;
    const int wave = tid >> 6;
    const int cc   = lane & 15;
    const int g    = lane >> 4;
    const int wr   = wave >> 1;        // wave row (0..1)
    const int wc   = wave & 1;         // wave col (0..1)

    // XCD swizzle: chunk of 64 consecutive ids per XCD -> head-per-XCD
    const int wg   = blockIdx.x;                 // 0..511, 512 % 8 == 0
    const int swz  = (wg & 7) * 64 + (wg >> 3);
    const int rowBase = (swz & 63) * 128;        // global j-row base
    const int head    = swz >> 6;

    // staging: wave covers 32 rows; 4 issues x 1024B (8 rows each)
    const int srow = lane >> 3;                  // 0..7
    const int scol = (lane & 7) * 8;             // bf16 elems
    const short* gA0 = hb  + (size_t)(rowBase + wave * 32 + srow) * D_ + scol;
    const short* gB0 = wrb + (size_t)(head * HD_ + wave * 32 + srow) * D_ + scol;
    char* lA = (char*)sA + wave * 32 * 128;
    char* lB = (char*)sB + wave * 32 * 128;

    f32x4 acc[4][4];
#pragma unroll
    for (int m = 0; m < 4; ++m)
#pragma unroll
        for (int n = 0; n < 4; ++n) acc[m][n] = (f32x4){0.f, 0.f, 0.f, 0.f};

    for (int k0 = 0; k0 < D_; k0 += 64) {
#pragma unroll
        for (int q = 0; q < 4; ++q)
            gload16(gA0 + k0 + q * 8 * D_, lA + q * 1024);
#pragma unroll
        for (int q = 0; q < 4; ++q)
            gload16(gB0 + k0 + q * 8 * D_, lB + q * 1024);
        __syncthreads();   // drains vmcnt(0) before barrier

#pragma unroll
        for (int kk = 0; kk < 2; ++kk) {
            bf16x8 aF[4], bF[4];
#pragma unroll
            for (int m = 0; m < 4; ++m)
                aF[m] = *(const bf16x8*)(sA + (wr * 64 + m * 16 + cc) * 64 + kk * 32 + g * 8);
#pragma unroll
            for (int n = 0; n < 4; ++n)
                bF[n] = *(const bf16x8*)(sB + (wc * 64 + n * 16 + cc) * 64 + kk * 32 + g * 8);
#pragma unroll
            for (int m = 0; m < 4; ++m)
#pragma unroll
                for (int n = 0; n < 4; ++n)
                    acc[m][n] = __builtin_amdgcn_mfma_f32_16x16x32_bf16(
                        aF[m], bF[n], acc[m][n], 0, 0, 0);
        }
        __syncthreads();   // protect LDS before next stage
    }

    // Epilogue: row = rowBase + wr*64 + m*16 + g*4 + reg,
    //           col_in_head = wc*64 + n*16 + cc
    float ar[4];
#pragma unroll
    for (int n = 0; n < 4; ++n) ar[n] = att_r[wc * 64 + n * 16 + cc];

#pragma unroll
    for (int m = 0; m < 4; ++m) {
#pragma unroll
        for (int r = 0; r < 4; ++r) {
            float p = 0.f;
#pragma unroll
            for (int n = 0; n < 4; ++n) {
                float v = acc[m][n][r];
                v = v > 0.f ? v : 0.01f * v;    // leaky
                p += v * ar[n];
            }
            p += __shfl_xor(p, 1); p += __shfl_xor(p, 2);
            p += __shfl_xor(p, 4); p += __shfl_xor(p, 8);
            if (cc == 0) part[wc][wr * 64 + m * 16 + g * 4 + r] = p;
        }
    }
    __syncthreads();
    if (tid < 128) {
        const int grow = rowBase + tid;
        const int b = grow >> 11, j = grow & (N_ - 1);
        sr[(size_t)(b * H_ + head) * N_ + j] = part[0][tid] + part[1][tid];
    }
}

// ---------------------------------------------------------------------------
// Kernel 2: w[bh, :] = softmax(sr[bh, :]) over N=2048, one block per (b,h)
// ---------------------------------------------------------------------------
__global__ __launch_bounds__(256) void k_softmax(
    const float* __restrict__ sr, float* __restrict__ w)
{
    const int bh = blockIdx.x;
    const int tid = threadIdx.x;
    const int lane = tid & 63, wave = tid >> 6;
    const float* s = sr + (size_t)bh * N_;
    float* o = w + (size_t)bh * N_;

    float v[8];
    float mx = -1e30f;
#pragma unroll
    for (int i = 0; i < 8; ++i) { v[i] = s[tid + i * 256]; mx = fmaxf(mx, v[i]); }
#pragma unroll
    for (int m = 1; m < 64; m <<= 1) mx = fmaxf(mx, __shfl_xor(mx, m));

    __shared__ float rmax[4], rsum[4];
    if (lane == 0) rmax[wave] = mx;
    __syncthreads();
    mx = fmaxf(fmaxf(rmax[0], rmax[1]), fmaxf(rmax[2], rmax[3]));

    float sum = 0.f;
#pragma unroll
    for (int i = 0; i < 8; ++i) { v[i] = expf(v[i] - mx); sum += v[i]; }
#pragma unroll
    for (int m = 1; m < 64; m <<= 1) sum += __shfl_xor(sum, m);
    if (lane == 0) rsum[wave] = sum;
    __syncthreads();
    sum = rsum[0] + rsum[1] + rsum[2] + rsum[3];
    const float inv = 1.f / sum;
#pragma unroll
    for (int i = 0; i < 8; ++i) o[tid + i * 256] = v[i] * inv;
}

// ---------------------------------------------------------------------------
// Kernel 3: partial hbar: hp[jc*32 + b*8 + h][d] = sum_{j in chunk} w*hb
// (reads bf16 copy of h: half the traffic; error ~0.003 abs, OK vs 0.1075)
// ---------------------------------------------------------------------------
__global__ __launch_bounds__(256) void k_hbar_partial(
    const short* __restrict__ hbm, const float* __restrict__ w,
    float* __restrict__ hp)
{
    const int dc = blockIdx.x;   // 0..3
    const int jc = blockIdx.y;   // 0..7
    const int b  = blockIdx.z;   // 0..3
    const int tid = threadIdx.x;
    const int d = dc * 256 + tid;

    __shared__ float wl[8][256];
#pragma unroll
    for (int hh = 0; hh < 8; ++hh)
        wl[hh][tid] = w[(size_t)(b * H_ + hh) * N_ + jc * 256 + tid];
    __syncthreads();

    float acc[8] = {0.f, 0.f, 0.f, 0.f, 0.f, 0.f, 0.f, 0.f};
    const short* hp0 = hbm + ((size_t)(b * N_ + jc * 256)) * D_ + d;
    for (int jj = 0; jj < 256; ++jj) {
        float hv = bf2f((unsigned short)hp0[(size_t)jj * D_]);
#pragma unroll
        for (int hh = 0; hh < 8; ++hh) acc[hh] += wl[hh][jj] * hv;
    }
#pragma unroll
    for (int hh = 0; hh < 8; ++hh)
        hp[((size_t)(jc * 32) + b * 8 + hh) * D_ + d] = acc[hh];
}

// ---------------------------------------------------------------------------
// Kernel 4: fused reduce + ctx. One block per (b,head):
//   x[e] = sum_jc hp[jc][b,head,e];  ctx[b,head*128+d'] = x . Wr[head*128+d']
// ---------------------------------------------------------------------------
__global__ __launch_bounds__(256) void k_ctx(
    const float* __restrict__ hp, const float* __restrict__ Wr,
    float* __restrict__ ctx)
{
    const int bh = blockIdx.x;           // b*8 + head
    const int b = bh >> 3, head = bh & 7;
    const int tid = threadIdx.x;
    const int lane = tid & 63, wave = tid >> 6;

    __shared__ float xs[1024];
    float4 s = {0.f, 0.f, 0.f, 0.f};
#pragma unroll
    for (int jc = 0; jc < 8; ++jc) {
        float4 v = ((const float4*)(hp + ((size_t)(jc * 32) + bh) * D_))[tid];
        s.x += v.x; s.y += v.y; s.z += v.z; s.w += v.w;
    }
    ((float4*)xs)[tid] = s;
    __syncthreads();

#pragma unroll
    for (int oo = 0; oo < 32; ++oo) {
        const int o = wave * 32 + oo;    // 0..127 within head
        const float* wrow = Wr + (size_t)(head * HD_ + o) * D_;
        float acc = 0.f;
#pragma unroll
        for (int it = 0; it < 4; ++it) {
            float4 wv = *(const float4*)(wrow + it * 256 + lane * 4);
            float4 xv = ((const float4*)xs)[it * 64 + lane];
            acc += wv.x * xv.x + wv.y * xv.y + wv.z * xv.z + wv.w * xv.w;
        }
#pragma unroll
        for (int m = 1; m < 64; m <<= 1) acc += __shfl_xor(acc, m);
        if (lane == 0) ctx[(size_t)b * D_ + head * HD_ + o] = acc;
    }
}

// ---------------------------------------------------------------------------
// Kernel 5: fvec[b, o] = sum_e ctx[b,e] * Wf[o,e]
// ---------------------------------------------------------------------------
__global__ __launch_bounds__(256) void k_fvec(
    const float* __restrict__ ctx, const float* __restrict__ Wf,
    float* __restrict__ fvec)
{
    const int o = blockIdx.x * 4 + (threadIdx.x >> 6);   // 0..4095
    const int lane = threadIdx.x & 63;
    const int b = o >> 10, orow = o & 1023;
    const float* x  = ctx + (size_t)b * D_;
    const float* wf = Wf + (size_t)orow * D_;
    float s = 0.f;
#pragma unroll
    for (int it = 0; it < 4; ++it) {
        float4 xv = *(const float4*)(x + it * 256 + lane * 4);
        float4 wv = *(const float4*)(wf + it * 256 + lane * 4);
        s += xv.x * wv.x + xv.y * wv.y + xv.z * wv.z + xv.w * wv.w;
    }
#pragma unroll
    for (int m = 1; m < 64; m <<= 1) s += __shfl_xor(s, m);
    if (lane == 0) fvec[o] = s;
}

// ---------------------------------------------------------------------------
// Kernel 6: out = LayerNorm(h + fvec[b]) * gamma + beta, one block per row.
// Runs LAST: overwrites d_out (which held the bf16 scratch copies).
// ---------------------------------------------------------------------------
__global__ __launch_bounds__(256) void k_ln(
    const float* __restrict__ h, const float* __restrict__ fvec,
    const float* __restrict__ gamma, const float* __restrict__ beta,
    float* __restrict__ out)
{
    const int row = blockIdx.x;
    const int b = row >> 11;
    const int tid = threadIdx.x;
    const int lane = tid & 63, wave = tid >> 6;

    float4 hv = *(const float4*)(h + (size_t)row * D_ + tid * 4);
    float4 fv = *(const float4*)(fvec + (size_t)b * D_ + tid * 4);
    const float y0 = hv.x + fv.x, y1 = hv.y + fv.y;
    const float y2 = hv.z + fv.z, y3 = hv.w + fv.w;

    float s = y0 + y1 + y2 + y3;
    float q = y0 * y0 + y1 * y1 + y2 * y2 + y3 * y3;
#pragma unroll
    for (int m = 1; m < 64; m <<= 1) { s += __shfl_xor(s, m); q += __shfl_xor(q, m); }

    __shared__ float rs[4], rq[4];
    if (lane == 0) { rs[wave] = s; rq[wave] = q; }
    __syncthreads();
    s = rs[0] + rs[1] + rs[2] + rs[3];
    q = rq[0] + rq[1] + rq[2] + rq[3];

    const float mu  = s * (1.f / D_);
    const float var = q * (1.f / D_) - mu * mu;
    const float inv = rsqrtf(var + 1e-5f);

    float4 gv = *(const float4*)(gamma + tid * 4);
    float4 bv = *(const float4*)(beta + tid * 4);
    float4 ov;
    ov.x = (y0 - mu) * inv * gv.x + bv.x;
    ov.y = (y1 - mu) * inv * gv.y + bv.y;
    ov.z = (y2 - mu) * inv * gv.z + bv.z;
    ov.w = (y3 - mu) * inv * gv.w + bv.w;
    *(float4*)(out + (size_t)row * D_ + tid * 4) = ov;
}

// ---------------------------------------------------------------------------
extern "C" void kernel_launch(void* const* d_in, const int* in_sizes, int n_in,
                              void* d_out, int out_size, void* d_ws, size_t ws_size,
                              hipStream_t stream) {
    const float* h     = (const float*)d_in[0];
    // d_in[1] = Wl  : dead (softmax over additive scores cancels sl)
    const float* Wr    = (const float*)d_in[2];
    // d_in[3] = att_l : dead
    const float* att_r = (const float*)d_in[4];
    const float* Wf    = (const float*)d_in[5];
    const float* gamma = (const float*)d_in[6];
    const float* beta  = (const float*)d_in[7];
    float* out = (float*)d_out;

    // bf16 scratch copies live in d_out (33.5 MB); overwritten last by k_ln.
    short* hb  = (short*)d_out;                             // 16 MB
    short* wrb = (short*)((char*)d_out + 16 * 1024 * 1024); // 2 MB

    char* ws = (char*)d_ws;
    float* sr   = (float*)(ws);                 // B*H*N   = 256 KB
    float* w    = (float*)(ws + 262144);        // B*H*N   = 256 KB
    float* hp   = (float*)(ws + 524288);        // 8*B*H*D = 1 MB
    float* ctx  = (float*)(ws + 1572864);       // B*D     = 16 KB
    float* fvec = (float*)(ws + 1589248);       // B*D     = 16 KB

    k_cvt<<<4096 + 512, 256, 0, stream>>>(h, hb, Wr, wrb);
    k_proj_sr<<<(B_ * N_ / 128) * H_, 256, 0, stream>>>(hb, wrb, att_r, sr);
    k_softmax<<<B_ * H_, 256, 0, stream>>>(sr, w);
    k_hbar_partial<<<dim3(4, 8, 4), 256, 0, stream>>>(hb, w, hp);
    k_ctx<<<B_ * H_, 256, 0, stream>>>(hp, Wr, ctx);
    k_fvec<<<1024, 256, 0, stream>>>(ctx, Wf, fvec);
    k_ln<<<B_ * N_, 256, 0, stream>>>(h, fvec, gamma, beta, out);
}

// Round 4
// 89.979 us; speedup vs baseline: 1.1003x; 1.1003x over previous
//
#include <hip/hip_runtime.h>
#include <hip/hip_bf16.h>

#define B_ 4
#define N_ 2048
#define D_ 1024
#define H_ 8
#define HD_ 128

typedef __attribute__((ext_vector_type(4))) float f32x4;
typedef __attribute__((ext_vector_type(8))) short bf16x8;

__device__ __forceinline__ short f2bf(float f) {
    unsigned u = __builtin_bit_cast(unsigned, f);
    u = (u + 0x7FFFu + ((u >> 16) & 1u)) >> 16;   // round-to-nearest-even
    return (short)u;
}
__device__ __forceinline__ float bf2f(unsigned short s) {
    unsigned u = (unsigned)s << 16;
    return __builtin_bit_cast(float, u);
}

typedef const __attribute__((address_space(1))) void* gas_t;
typedef __attribute__((address_space(3))) void* las_t;

__device__ __forceinline__ void gload16(const void* g, void* l) {
    // lane i's 16B from per-lane g -> wave-uniform LDS base + lane*16
    __builtin_amdgcn_global_load_lds((gas_t)g, (las_t)l, 16, 0, 0);
}

// ---------------------------------------------------------------------------
// Kernel 0: fp32 -> bf16 pack for h (4096 blocks) and Wr (512 blocks), fused.
// ---------------------------------------------------------------------------
__global__ __launch_bounds__(256) void k_cvt(
    const float* __restrict__ h, short* __restrict__ hb,
    const float* __restrict__ Wr, short* __restrict__ wrb)
{
    int blk = blockIdx.x;
    const float* src;
    short* dst;
    int i;
    if (blk < 4096) { src = h;  dst = hb;  i = blk * 256 + threadIdx.x; }
    else            { src = Wr; dst = wrb; i = (blk - 4096) * 256 + threadIdx.x; }
    float4 a = ((const float4*)src)[i * 2];
    float4 b = ((const float4*)src)[i * 2 + 1];
    bf16x8 o;
    o[0] = f2bf(a.x); o[1] = f2bf(a.y); o[2] = f2bf(a.z); o[3] = f2bf(a.w);
    o[4] = f2bf(b.x); o[5] = f2bf(b.y); o[6] = f2bf(b.z); o[7] = f2bf(b.w);
    ((bf16x8*)dst)[i] = o;
}

// ---------------------------------------------------------------------------
// Kernel 1: GEMM fr = h @ Wr^T (128x128 tile, BK=64, 8 waves of 64x32),
// fused epilogue: sr[b,head,j] = sum_c leaky(fr[j, head*128+c]) * att_r[c].
// Grid: 512 blocks, IDENTITY order (row-tile fast -> A tiles pinned per XCD
// across heads; the R3 head-chunk swizzle thrashed L2 and regressed).
// LDS bank conflicts: linear dest for global_load_lds + XOR-preswizzled
// GLOBAL source + same XOR on ds_read (rule #21) -> 2-way (free).
// ---------------------------------------------------------------------------
__global__ __launch_bounds__(512) void k_proj_sr(
    const short* __restrict__ hb, const short* __restrict__ wrb,
    const float* __restrict__ att_r, float* __restrict__ sr)
{
    __shared__ short sA[128 * 64];     // 16 KB, swizzled [row][col^((row&7)*8)]
    __shared__ short sB[128 * 64];     // 16 KB
    __shared__ float part[4][128];

    const int tid  = threadIdx.x;
    const int lane = tid & 63;
    const int wave = tid >> 6;         // 0..7
    const int cc   = lane & 15;
    const int g    = lane >> 4;
    const int wr   = wave >> 2;        // 0..1 : rows wr*64
    const int wc   = wave & 3;         // 0..3 : cols wc*32
    const int rowBase = (blockIdx.x & 63) * 128;
    const int head    = blockIdx.x >> 6;

    // staging: wave stages rows [wave*16, +16) of A and B, 2 issues each.
    // lane l covers (row = l>>3, colbyte = (l&7)*16); source col is XOR'd so
    // the linear LDS write realizes the swizzled layout.
    const int srow = lane >> 3;                       // 0..7
    const int scol = ((lane & 7) ^ srow) * 8;         // bf16 elems (16B units)
    const short* gA0 = hb  + (size_t)(rowBase + wave * 16 + srow) * D_ + scol;
    const short* gB0 = wrb + (size_t)(head * HD_ + wave * 16 + srow) * D_ + scol;
    char* lA = (char*)sA + wave * 16 * 128;
    char* lB = (char*)sB + wave * 16 * 128;

    f32x4 acc[4][2];
#pragma unroll
    for (int m = 0; m < 4; ++m)
#pragma unroll
        for (int n = 0; n < 2; ++n) acc[m][n] = (f32x4){0.f, 0.f, 0.f, 0.f};

    for (int k0 = 0; k0 < D_; k0 += 64) {
        gload16(gA0 + k0,           lA);
        gload16(gA0 + k0 + 8 * D_,  lA + 1024);
        gload16(gB0 + k0,           lB);
        gload16(gB0 + k0 + 8 * D_,  lB + 1024);
        __syncthreads();   // drains vmcnt(0) before barrier

#pragma unroll
        for (int kk = 0; kk < 2; ++kk) {
            const int kswz = (kk * 64 + g * 16) ^ ((cc & 7) << 4);  // byte off
            bf16x8 aF[4], bF[2];
#pragma unroll
            for (int m = 0; m < 4; ++m)
                aF[m] = *(const bf16x8*)((const char*)sA +
                         (wr * 64 + m * 16 + cc) * 128 + kswz);
#pragma unroll
            for (int n = 0; n < 2; ++n)
                bF[n] = *(const bf16x8*)((const char*)sB +
                         (wc * 32 + n * 16 + cc) * 128 + kswz);
#pragma unroll
            for (int m = 0; m < 4; ++m)
#pragma unroll
                for (int n = 0; n < 2; ++n)
                    acc[m][n] = __builtin_amdgcn_mfma_f32_16x16x32_bf16(
                        aF[m], bF[n], acc[m][n], 0, 0, 0);
        }
        __syncthreads();   // protect LDS before next stage
    }

    // Epilogue: row = rowBase + wr*64 + m*16 + g*4 + reg,
    //           col_in_head = wc*32 + n*16 + cc
    float ar[2];
#pragma unroll
    for (int n = 0; n < 2; ++n) ar[n] = att_r[wc * 32 + n * 16 + cc];

#pragma unroll
    for (int m = 0; m < 4; ++m) {
#pragma unroll
        for (int r = 0; r < 4; ++r) {
            float p = 0.f;
#pragma unroll
            for (int n = 0; n < 2; ++n) {
                float v = acc[m][n][r];
                v = v > 0.f ? v : 0.01f * v;    // leaky
                p += v * ar[n];
            }
            p += __shfl_xor(p, 1); p += __shfl_xor(p, 2);
            p += __shfl_xor(p, 4); p += __shfl_xor(p, 8);
            if (cc == 0) part[wc][wr * 64 + m * 16 + g * 4 + r] = p;
        }
    }
    __syncthreads();
    if (tid < 128) {
        const int grow = rowBase + tid;
        const int b = grow >> 11, j = grow & (N_ - 1);
        sr[(size_t)(b * H_ + head) * N_ + j] =
            part[0][tid] + part[1][tid] + part[2][tid] + part[3][tid];
    }
}

// ---------------------------------------------------------------------------
// Kernel 2: w[bh, :] = softmax(sr[bh, :]) over N=2048, one block per (b,h)
// ---------------------------------------------------------------------------
__global__ __launch_bounds__(256) void k_softmax(
    const float* __restrict__ sr, float* __restrict__ w)
{
    const int bh = blockIdx.x;
    const int tid = threadIdx.x;
    const int lane = tid & 63, wave = tid >> 6;
    const float* s = sr + (size_t)bh * N_;
    float* o = w + (size_t)bh * N_;

    float v[8];
    float mx = -1e30f;
#pragma unroll
    for (int i = 0; i < 8; ++i) { v[i] = s[tid + i * 256]; mx = fmaxf(mx, v[i]); }
#pragma unroll
    for (int m = 1; m < 64; m <<= 1) mx = fmaxf(mx, __shfl_xor(mx, m));

    __shared__ float rmax[4], rsum[4];
    if (lane == 0) rmax[wave] = mx;
    __syncthreads();
    mx = fmaxf(fmaxf(rmax[0], rmax[1]), fmaxf(rmax[2], rmax[3]));

    float sum = 0.f;
#pragma unroll
    for (int i = 0; i < 8; ++i) { v[i] = expf(v[i] - mx); sum += v[i]; }
#pragma unroll
    for (int m = 1; m < 64; m <<= 1) sum += __shfl_xor(sum, m);
    if (lane == 0) rsum[wave] = sum;
    __syncthreads();
    sum = rsum[0] + rsum[1] + rsum[2] + rsum[3];
    const float inv = 1.f / sum;
#pragma unroll
    for (int i = 0; i < 8; ++i) o[tid + i * 256] = v[i] * inv;
}

// ---------------------------------------------------------------------------
// Kernel 3: partial hbar: hp[jc*32 + b*8 + h][d] = sum_{j in chunk} w*hb
// ---------------------------------------------------------------------------
__global__ __launch_bounds__(256) void k_hbar_partial(
    const short* __restrict__ hbm, const float* __restrict__ w,
    float* __restrict__ hp)
{
    const int dc = blockIdx.x;   // 0..3
    const int jc = blockIdx.y;   // 0..7
    const int b  = blockIdx.z;   // 0..3
    const int tid = threadIdx.x;
    const int d = dc * 256 + tid;

    __shared__ float wl[8][256];
#pragma unroll
    for (int hh = 0; hh < 8; ++hh)
        wl[hh][tid] = w[(size_t)(b * H_ + hh) * N_ + jc * 256 + tid];
    __syncthreads();

    float acc[8] = {0.f, 0.f, 0.f, 0.f, 0.f, 0.f, 0.f, 0.f};
    const short* hp0 = hbm + ((size_t)(b * N_ + jc * 256)) * D_ + d;
    for (int jj = 0; jj < 256; ++jj) {
        float hv = bf2f((unsigned short)hp0[(size_t)jj * D_]);
#pragma unroll
        for (int hh = 0; hh < 8; ++hh) acc[hh] += wl[hh][jj] * hv;
    }
#pragma unroll
    for (int hh = 0; hh < 8; ++hh)
        hp[((size_t)(jc * 32) + b * 8 + hh) * D_ + d] = acc[hh];
}

// ---------------------------------------------------------------------------
// Kernel 4: fused reduce + ctx. One block per (b,head):
//   x[e] = sum_jc hp[jc][b,head,e];  ctx[b,head*128+d'] = x . Wr[head*128+d']
// ---------------------------------------------------------------------------
__global__ __launch_bounds__(256) void k_ctx(
    const float* __restrict__ hp, const float* __restrict__ Wr,
    float* __restrict__ ctx)
{
    const int bh = blockIdx.x;           // b*8 + head
    const int b = bh >> 3, head = bh & 7;
    const int tid = threadIdx.x;
    const int lane = tid & 63, wave = tid >> 6;

    __shared__ float xs[1024];
    float4 s = {0.f, 0.f, 0.f, 0.f};
#pragma unroll
    for (int jc = 0; jc < 8; ++jc) {
        float4 v = ((const float4*)(hp + ((size_t)(jc * 32) + bh) * D_))[tid];
        s.x += v.x; s.y += v.y; s.z += v.z; s.w += v.w;
    }
    ((float4*)xs)[tid] = s;
    __syncthreads();

#pragma unroll
    for (int oo = 0; oo < 32; ++oo) {
        const int o = wave * 32 + oo;    // 0..127 within head
        const float* wrow = Wr + (size_t)(head * HD_ + o) * D_;
        float acc = 0.f;
#pragma unroll
        for (int it = 0; it < 4; ++it) {
            float4 wv = *(const float4*)(wrow + it * 256 + lane * 4);
            float4 xv = ((const float4*)xs)[it * 64 + lane];
            acc += wv.x * xv.x + wv.y * xv.y + wv.z * xv.z + wv.w * xv.w;
        }
#pragma unroll
        for (int m = 1; m < 64; m <<= 1) acc += __shfl_xor(acc, m);
        if (lane == 0) ctx[(size_t)b * D_ + head * HD_ + o] = acc;
    }
}

// ---------------------------------------------------------------------------
// Kernel 5: fvec[b, o] = sum_e ctx[b,e] * Wf[o,e]
// ---------------------------------------------------------------------------
__global__ __launch_bounds__(256) void k_fvec(
    const float* __restrict__ ctx, const float* __restrict__ Wf,
    float* __restrict__ fvec)
{
    const int o = blockIdx.x * 4 + (threadIdx.x >> 6);   // 0..4095
    const int lane = threadIdx.x & 63;
    const int b = o >> 10, orow = o & 1023;
    const float* x  = ctx + (size_t)b * D_;
    const float* wf = Wf + (size_t)orow * D_;
    float s = 0.f;
#pragma unroll
    for (int it = 0; it < 4; ++it) {
        float4 xv = *(const float4*)(x + it * 256 + lane * 4);
        float4 wv = *(const float4*)(wf + it * 256 + lane * 4);
        s += xv.x * wv.x + xv.y * wv.y + xv.z * wv.z + xv.w * wv.w;
    }
#pragma unroll
    for (int m = 1; m < 64; m <<= 1) s += __shfl_xor(s, m);
    if (lane == 0) fvec[o] = s;
}

// ---------------------------------------------------------------------------
// Kernel 6: out = LayerNorm(h + fvec[b]) * gamma + beta, one block per row.
// Runs LAST: overwrites d_out (which held the bf16 scratch copies).
// ---------------------------------------------------------------------------
__global__ __launch_bounds__(256) void k_ln(
    const float* __restrict__ h, const float* __restrict__ fvec,
    const float* __restrict__ gamma, const float* __restrict__ beta,
    float* __restrict__ out)
{
    const int row = blockIdx.x;
    const int b = row >> 11;
    const int tid = threadIdx.x;
    const int lane = tid & 63, wave = tid >> 6;

    float4 hv = *(const float4*)(h + (size_t)row * D_ + tid * 4);
    float4 fv = *(const float4*)(fvec + (size_t)b * D_ + tid * 4);
    const float y0 = hv.x + fv.x, y1 = hv.y + fv.y;
    const float y2 = hv.z + fv.z, y3 = hv.w + fv.w;

    float s = y0 + y1 + y2 + y3;
    float q = y0 * y0 + y1 * y1 + y2 * y2 + y3 * y3;
#pragma unroll
    for (int m = 1; m < 64; m <<= 1) { s += __shfl_xor(s, m); q += __shfl_xor(q, m); }

    __shared__ float rs[4], rq[4];
    if (lane == 0) { rs[wave] = s; rq[wave] = q; }
    __syncthreads();
    s = rs[0] + rs[1] + rs[2] + rs[3];
    q = rq[0] + rq[1] + rq[2] + rq[3];

    const float mu  = s * (1.f / D_);
    const float var = q * (1.f / D_) - mu * mu;
    const float inv = rsqrtf(var + 1e-5f);

    float4 gv = *(const float4*)(gamma + tid * 4);
    float4 bv = *(const float4*)(beta + tid * 4);
    float4 ov;
    ov.x = (y0 - mu) * inv * gv.x + bv.x;
    ov.y = (y1 - mu) * inv * gv.y + bv.y;
    ov.z = (y2 - mu) * inv * gv.z + bv.z;
    ov.w = (y3 - mu) * inv * gv.w + bv.w;
    *(float4*)(out + (size_t)row * D_ + tid * 4) = ov;
}

// ---------------------------------------------------------------------------
extern "C" void kernel_launch(void* const* d_in, const int* in_sizes, int n_in,
                              void* d_out, int out_size, void* d_ws, size_t ws_size,
                              hipStream_t stream) {
    const float* h     = (const float*)d_in[0];
    // d_in[1] = Wl  : dead (softmax over additive scores cancels sl)
    const float* Wr    = (const float*)d_in[2];
    // d_in[3] = att_l : dead
    const float* att_r = (const float*)d_in[4];
    const float* Wf    = (const float*)d_in[5];
    const float* gamma = (const float*)d_in[6];
    const float* beta  = (const float*)d_in[7];
    float* out = (float*)d_out;

    // bf16 scratch copies live in d_out (33.5 MB); overwritten last by k_ln.
    short* hb  = (short*)d_out;                             // 16 MB
    short* wrb = (short*)((char*)d_out + 16 * 1024 * 1024); // 2 MB

    char* ws = (char*)d_ws;
    float* sr   = (float*)(ws);                 // B*H*N   = 256 KB
    float* w    = (float*)(ws + 262144);        // B*H*N   = 256 KB
    float* hp   = (float*)(ws + 524288);        // 8*B*H*D = 1 MB
    float* ctx  = (float*)(ws + 1572864);       // B*D     = 16 KB
    float* fvec = (float*)(ws + 1589248);       // B*D     = 16 KB

    k_cvt<<<4096 + 512, 256, 0, stream>>>(h, hb, Wr, wrb);
    k_proj_sr<<<(B_ * N_ / 128) * H_, 512, 0, stream>>>(hb, wrb, att_r, sr);
    k_softmax<<<B_ * H_, 256, 0, stream>>>(sr, w);
    k_hbar_partial<<<dim3(4, 8, 4), 256, 0, stream>>>(hb, w, hp);
    k_ctx<<<B_ * H_, 256, 0, stream>>>(hp, Wr, ctx);
    k_fvec<<<1024, 256, 0, stream>>>(ctx, Wf, fvec);
    k_ln<<<B_ * N_, 256, 0, stream>>>(h, fvec, gamma, beta, out);
}